// Round 14
// baseline (1266.740 us; speedup 1.0000x reference)
//
#include <hip/hip_runtime.h>

#define TOKN 65536   // 128*512
#define SQ 512
#define BB 128
#define DD 100
#define APAD 132

typedef unsigned short bf16t;
typedef __attribute__((ext_vector_type(8))) short bf16x8;
typedef __attribute__((ext_vector_type(4))) float floatx4;
typedef __attribute__((ext_vector_type(2))) _Float16 half2t;

__device__ __forceinline__ float bf2f(bf16t v) {
  unsigned u = ((unsigned)v) << 16;
  return __uint_as_float(u);
}
__device__ __forceinline__ bf16t f2bf(float x) {
  unsigned u = __float_as_uint(x);
  unsigned r = u + 0x7FFFu + ((u >> 16) & 1u);
  return (bf16t)(r >> 16);
}
__device__ __forceinline__ float2 ldpair(const float* p) { return *(const float2*)p; }
__device__ __forceinline__ float2 ldpair(const bf16t* p) {
  unsigned u = *(const unsigned*)p;
  float2 r;
  r.x = __uint_as_float(u << 16);
  r.y = __uint_as_float(u & 0xFFFF0000u);
  return r;
}
__device__ __forceinline__ half2t u2h2(unsigned u) {
  union { unsigned u; half2t h; } x; x.u = u; return x.h;
}

__device__ __forceinline__ float sigm(float x) { return 1.f / (1.f + __expf(-x)); }
__device__ __forceinline__ float tanhx(float x) { return 1.f - 2.f / (1.f + __expf(2.f * x)); }

#if __has_builtin(__builtin_amdgcn_fdot2)
#define DOT2(hu, wu, acc) acc = __builtin_amdgcn_fdot2(u2h2(hu), u2h2(wu), acc, false);
#else
#define DOT2(hu, wu, acc) { half2t hh = u2h2(hu), ww = u2h2(wu); \
  acc = fmaf((float)hh[0], (float)ww[0], acc); \
  acc = fmaf((float)hh[1], (float)ww[1], acc); }
#endif

// ---------------- embedding + mask: e[TOKN][64] bf16 (K-padded) ----------------
__global__ __launch_bounds__(256) void embed_kernel(
    const int* __restrict__ x1, const int* __restrict__ x2,
    const float* __restrict__ emb,
    bf16t* __restrict__ e1, bf16t* __restrict__ e2,
    float* __restrict__ m1, float* __restrict__ m2) {
  const int which = blockIdx.y;
  const int* __restrict__ x = which ? x2 : x1;
  bf16t* __restrict__ e = which ? e2 : e1;
  float* __restrict__ m = which ? m2 : m1;
  int idx = blockIdx.x * 256 + threadIdx.x;  // over TOKN*64
  int t = idx >> 6, d = idx & 63;
  int tok = x[t];
  float mk = (tok != 0) ? 1.f : 0.f;
  float v = (d < 50) ? emb[tok * 50 + d] * mk : 0.f;
  e[idx] = f2bf(v);
  if (d == 0) m[t] = mk;
}

// ---------------- zero K-pad columns 100..127 of enc1/enc2 ----------------
__global__ __launch_bounds__(256) void padzero_kernel(
    unsigned* __restrict__ p1, unsigned* __restrict__ p2) {
  int idx = blockIdx.x * 256 + threadIdx.x;  // TOKN*14 dwords
  if (idx >= TOKN * 14) return;
  int t = idx / 14, d = idx - t * 14;
  p1[(size_t)t * 64 + 50 + d] = 0u;
  p2[(size_t)t * 64 + 50 + d] = 0u;
}

// ---------------- weight prep ----------------
// sec0: w1T[2][208][64]; sec1: w2T[2][208][128]; sec2: wdT[128][384]
// sec3: whP[4][25][200] packed half2 from {b1f,b1b,b2f,b2b}_Wh [50][200]
__global__ __launch_bounds__(256) void wprep_kernel(
    const float* __restrict__ w1f, const float* __restrict__ w1b,
    const float* __restrict__ w2f, const float* __restrict__ w2b,
    const float* __restrict__ dW,
    const float* __restrict__ h1f, const float* __restrict__ h1b,
    const float* __restrict__ h2f, const float* __restrict__ h2b,
    bf16t* __restrict__ w1T, bf16t* __restrict__ w2T, bf16t* __restrict__ wdT,
    unsigned* __restrict__ whP) {
  int idx = blockIdx.x * 256 + threadIdx.x;
  int sec = blockIdx.y;
  if (sec == 0) {
    if (idx >= 2 * 208 * 64) return;
    int d = idx / (208 * 64), r = idx % (208 * 64);
    int n = r >> 6, k = r & 63;
    const float* W = d ? w1b : w1f;
    float v = (n < 200 && k < 50) ? W[k * 200 + n] : 0.f;
    w1T[idx] = f2bf(v);
  } else if (sec == 1) {
    if (idx >= 2 * 208 * 128) return;
    int d = idx / (208 * 128), r = idx % (208 * 128);
    int n = r >> 7, k = r & 127;
    const float* W = d ? w2b : w2f;
    float v = (n < 200 && k < 100) ? W[k * 200 + n] : 0.f;
    w2T[idx] = f2bf(v);
  } else if (sec == 2) {
    if (idx >= 128 * 384) return;
    int n = idx / 384, kv = idx % 384;
    int reg = kv >> 7, kk = kv & 127;
    float v = 0.f;
    if (n < 100 && kk < 100) {
      if (reg == 0) v = dW[kk * 100 + n] + dW[(300 + kk) * 100 + n];
      else if (reg == 1) v = dW[(100 + kk) * 100 + n] - dW[(300 + kk) * 100 + n];
      else v = dW[(200 + kk) * 100 + n];
    }
    wdT[idx] = f2bf(v);
  } else {
    if (idx >= 4 * 25 * 200) return;
    int sd = idx / 5000, r = idx % 5000;
    int k2 = r / 200, colx = r % 200;
    const float* W = (sd == 0) ? h1f : (sd == 1) ? h1b : (sd == 2) ? h2f : h2b;
    float v0 = W[(2 * k2) * 200 + colx];
    float v1 = W[(2 * k2 + 1) * 200 + colx];
    union { _Float16 h[2]; unsigned u; } p;
    p.h[0] = (_Float16)v0;
    p.h[1] = (_Float16)v1;
    whP[idx] = p.u;
  }
}

// ---------------- MFMA xz GEMM: xzT[combo][b][200][512] = A@Wx + b ----------------
template <int KP>
__global__ __launch_bounds__(256) void xz_mfma(
    const bf16t* __restrict__ A1, const bf16t* __restrict__ A2,
    const bf16t* __restrict__ WT,
    const float* __restrict__ bf_, const float* __restrict__ bb_,
    bf16t* __restrict__ out) {
  const int combo = blockIdx.y;
  const bf16t* __restrict__ A = (combo < 2) ? A1 : A2;
  const bf16t* __restrict__ W = WT + (size_t)(combo & 1) * 208 * KP;
  const float* __restrict__ bias = (combo & 1) ? bb_ : bf_;
  bf16t* __restrict__ O = out + (size_t)combo * TOKN * 200;
  const int tid = threadIdx.x;
  const int wave = tid >> 6, lane = tid & 63;
  const int m0 = blockIdx.x * 64 + wave * 16;
  const int l15 = lane & 15, quad = lane >> 4;
  floatx4 acc[13];
#pragma unroll
  for (int nt = 0; nt < 13; ++nt) acc[nt] = (floatx4){0.f, 0.f, 0.f, 0.f};
  const bf16t* __restrict__ arow = A + (size_t)(m0 + l15) * KP + quad * 8;
  const bf16t* __restrict__ wb = W + (size_t)l15 * KP + quad * 8;
#pragma unroll
  for (int ks = 0; ks < KP / 32; ++ks) {
    bf16x8 a = *(const bf16x8*)(arow + ks * 32);
#pragma unroll
    for (int nt = 0; nt < 13; ++nt) {
      bf16x8 b = *(const bf16x8*)(wb + (size_t)nt * 16 * KP + ks * 32);
      acc[nt] = __builtin_amdgcn_mfma_f32_16x16x32_bf16(a, b, acc[nt], 0, 0, 0);
    }
  }
  const int crow = m0 + quad * 4;
  const int bidx = crow >> 9;
  const int trow = crow & 511;
#pragma unroll
  for (int nt = 0; nt < 13; ++nt) {
    int n = nt * 16 + l15;
    if (n < 200) {
      float bn = bias[n];
      union { bf16t h[4]; uint2 u2; } pk;
#pragma unroll
      for (int r = 0; r < 4; ++r) pk.h[r] = f2bf(acc[nt][r] + bn);
      *(uint2*)&O[((size_t)bidx * 200 + n) * SQ + trow] = pk.u2;
    }
  }
}

// ---------------- MFMA dense: map = relu([e,d,e*d]@W' + b), out [t][128] ----------------
__global__ __launch_bounds__(256) void dense_mfma(
    const bf16t* __restrict__ enc1, const bf16t* __restrict__ enc2,
    const bf16t* __restrict__ d1b, const bf16t* __restrict__ d2b,
    const bf16t* __restrict__ wdT, const float* __restrict__ bias,
    bf16t* __restrict__ map1, bf16t* __restrict__ map2) {
  const int inp = blockIdx.y;
  const bf16t* __restrict__ E = inp ? enc2 : enc1;
  const bf16t* __restrict__ Db = inp ? d2b : d1b;
  bf16t* __restrict__ O = inp ? map2 : map1;
  const int tid = threadIdx.x;
  const int wave = tid >> 6, lane = tid & 63;
  const int m0 = blockIdx.x * 64 + wave * 16;
  const int l15 = lane & 15, quad = lane >> 4;
  floatx4 acc[8];
#pragma unroll
  for (int nt = 0; nt < 8; ++nt) acc[nt] = (floatx4){0.f, 0.f, 0.f, 0.f};
  const bf16t* __restrict__ erow = E + (size_t)(m0 + l15) * 128 + quad * 8;
  const bf16t* __restrict__ drow = Db + (size_t)(m0 + l15) * 128 + quad * 8;
  const bf16t* __restrict__ wb = wdT + (size_t)l15 * 384 + quad * 8;
#pragma unroll
  for (int ks = 0; ks < 4; ++ks) {
    bf16x8 ae = *(const bf16x8*)(erow + ks * 32);
    bf16x8 ad = *(const bf16x8*)(drow + ks * 32);
    bf16x8 aed;
#pragma unroll
    for (int q = 0; q < 8; ++q) {
      float pe = bf2f((bf16t)ae[q]);
      float pd = bf2f((bf16t)ad[q]);
      aed[q] = (short)f2bf(pe * pd);
    }
#pragma unroll
    for (int nt = 0; nt < 8; ++nt) {
      const bf16t* wn = wb + (size_t)nt * 16 * 384 + ks * 32;
      bf16x8 b0 = *(const bf16x8*)(wn);
      acc[nt] = __builtin_amdgcn_mfma_f32_16x16x32_bf16(ae, b0, acc[nt], 0, 0, 0);
      bf16x8 b1 = *(const bf16x8*)(wn + 128);
      acc[nt] = __builtin_amdgcn_mfma_f32_16x16x32_bf16(ad, b1, acc[nt], 0, 0, 0);
      bf16x8 b2 = *(const bf16x8*)(wn + 256);
      acc[nt] = __builtin_amdgcn_mfma_f32_16x16x32_bf16(aed, b2, acc[nt], 0, 0, 0);
    }
  }
  const int crow = m0 + quad * 4;
#pragma unroll
  for (int nt = 0; nt < 8; ++nt) {
    int n = nt * 16 + l15;
    float bn = (n < 100) ? bias[n] : 0.f;
#pragma unroll
    for (int r = 0; r < 4; ++r) {
      float v = (n < 100) ? fmaxf(acc[nt][r] + bn, 0.f) : 0.f;
      O[(size_t)(crow + r) * 128 + n] = f2bf(v);
    }
  }
}

// ---------------- LSTM scan: gate-split x batch-pair ----------------
// 256 blocks x 128 threads (2 waves).  Wave w owns gates {w*100..w*100+99}
// (w=0: i,f; w=1: g,o) -> 50 weight dwords/lane (RA-resident range).  Each
// block advances TWO chains (batches p and p+64 of the same scan): 100 dot2
// per wave per step serve 2 chains, and the chains' latency interleaves.
// Waves exchange gate pre-activations via LDS (2 two-wave barriers/step);
// wave0 cell-updates chain A, wave1 chain B.
__global__ __launch_bounds__(128)
__attribute__((amdgpu_waves_per_eu(1, 2)))
void lstm_scan(
    const bf16t* __restrict__ xzT,      // [4][128][200][512]
    const unsigned* __restrict__ whPL,  // [2][25][200] packed half2
    bf16t* __restrict__ out1, bf16t* __restrict__ out2,
    const float* __restrict__ m1, const float* __restrict__ m2,
    int hasMask) {
  const int blk = blockIdx.x;          // 256 blocks
  const int scan = blk >> 6;
  const int pair = blk & 63;
  const int inp = scan >> 1;
  const int dir = scan & 1;
  const int tid = threadIdx.x;
  const int w = tid >> 6;              // wave: gate group
  const int u = tid & 63;
  const bool act_l = (u < 50);
  const int uc = act_l ? u : 0;
  const int bA = pair, bB = pair + 64;
  const int myB = w ? bB : bA;         // chain this wave cell-updates/outputs
  // z streams: [gate-in-wave][chain]
  const bf16t* __restrict__ xA0 =
      xzT + (((size_t)scan * 128 + bA) * 200 + w * 100 + uc) * SQ;
  const bf16t* __restrict__ xA1 = xA0 + (size_t)50 * SQ;
  const bf16t* __restrict__ xB0 =
      xzT + (((size_t)scan * 128 + bB) * 200 + w * 100 + uc) * SQ;
  const bf16t* __restrict__ xB1 = xB0 + (size_t)50 * SQ;
  bf16t* __restrict__ outp = (inp ? out2 : out1) + (size_t)myB * SQ * 128 + dir * 50;
  const float* __restrict__ mk = (inp ? m2 : m1) + myB * SQ;
  __shared__ __align__(16) unsigned hbuf[2][2][32];  // [chain][parity] packed f16
  __shared__ __align__(8) float2 actx[2][2][50];     // [wave][chain][unit]

  const unsigned* __restrict__ wsrc = whPL + dir * 5000;
  unsigned wg0[25], wg1[25];
#pragma unroll
  for (int k2 = 0; k2 < 25; ++k2) {
    wg0[k2] = wsrc[k2 * 200 + w * 100 + uc];
    wg1[k2] = wsrc[k2 * 200 + w * 100 + 50 + uc];
  }
#pragma unroll
  for (int k2 = 0; k2 < 25; ++k2) {
    asm volatile("" : "+v"(wg0[k2]));
    asm volatile("" : "+v"(wg1[k2]));
  }

  ((unsigned*)hbuf)[tid] = 0;  // 128 dwords total
  float c = 0.f;
  const float4* mk4 = (const float4*)mk;
  __syncthreads();

  for (int g8 = 0; g8 < SQ / 8; ++g8) {
    // load + unpack this group's z (4 streams x 8 steps), honoring dir
    int r0 = dir ? (SQ - 8 - 8 * g8) : (8 * g8);
    uint4 cur[4];
    cur[0] = *(const uint4*)(xA0 + r0);
    cur[1] = *(const uint4*)(xA1 + r0);
    cur[2] = *(const uint4*)(xB0 + r0);
    cur[3] = *(const uint4*)(xB1 + r0);
    float zst[4][8];
#pragma unroll
    for (int gg = 0; gg < 4; ++gg) {
      unsigned dw[4] = {cur[gg].x, cur[gg].y, cur[gg].z, cur[gg].w};
#pragma unroll
      for (int p = 0; p < 4; ++p) {
        float lo = __uint_as_float(dw[p] << 16);
        float hi = __uint_as_float(dw[p] & 0xFFFF0000u);
        if (dir) { zst[gg][7 - 2 * p] = lo; zst[gg][6 - 2 * p] = hi; }
        else     { zst[gg][2 * p] = lo;     zst[gg][2 * p + 1] = hi; }
      }
    }
    float mva[8];
    if (hasMask) {
      float4 ma = mk4[2 * g8], mb = mk4[2 * g8 + 1];
      mva[0] = ma.x; mva[1] = ma.y; mva[2] = ma.z; mva[3] = ma.w;
      mva[4] = mb.x; mva[5] = mb.y; mva[6] = mb.z; mva[7] = mb.w;
    }
    bf16t hs8[8];
#pragma unroll
    for (int j = 0; j < 8; ++j) {
      const int par = j & 1;
      // read both chains' h (packed f16)
      const uint4* hA = (const uint4*)&hbuf[0][par][0];
      uint4 a0 = hA[0], a1 = hA[1], a2 = hA[2], a3 = hA[3], a4 = hA[4], a5 = hA[5];
      unsigned aL = hbuf[0][par][24];
      const uint4* hB = (const uint4*)&hbuf[1][par][0];
      uint4 b0 = hB[0], b1 = hB[1], b2 = hB[2], b3 = hB[3], b4 = hB[4], b5 = hB[5];
      unsigned bL = hbuf[1][par][24];
      unsigned hdA[25] = {a0.x, a0.y, a0.z, a0.w, a1.x, a1.y, a1.z, a1.w,
                          a2.x, a2.y, a2.z, a2.w, a3.x, a3.y, a3.z, a3.w,
                          a4.x, a4.y, a4.z, a4.w, a5.x, a5.y, a5.z, a5.w, aL};
      unsigned hdB[25] = {b0.x, b0.y, b0.z, b0.w, b1.x, b1.y, b1.z, b1.w,
                          b2.x, b2.y, b2.z, b2.w, b3.x, b3.y, b3.z, b3.w,
                          b4.x, b4.y, b4.z, b4.w, b5.x, b5.y, b5.z, b5.w, bL};
      // dots: 2 gates x 2 chains, 2 accumulators each
      float rA0a = zst[0][j], rA0b = 0.f;
      float rA1a = zst[1][j], rA1b = 0.f;
      float rB0a = zst[2][j], rB0b = 0.f;
      float rB1a = zst[3][j], rB1b = 0.f;
#pragma unroll
      for (int k2 = 0; k2 < 24; k2 += 2) {
        DOT2(hdA[k2], wg0[k2], rA0a)     DOT2(hdA[k2 + 1], wg0[k2 + 1], rA0b)
        DOT2(hdA[k2], wg1[k2], rA1a)     DOT2(hdA[k2 + 1], wg1[k2 + 1], rA1b)
        DOT2(hdB[k2], wg0[k2], rB0a)     DOT2(hdB[k2 + 1], wg0[k2 + 1], rB0b)
        DOT2(hdB[k2], wg1[k2], rB1a)     DOT2(hdB[k2 + 1], wg1[k2 + 1], rB1b)
      }
      DOT2(hdA[24], wg0[24], rA0a)
      DOT2(hdA[24], wg1[24], rA1a)
      DOT2(hdB[24], wg0[24], rB0a)
      DOT2(hdB[24], wg1[24], rB1a)
      float rA0 = rA0a + rA0b, rA1 = rA1a + rA1b;
      float rB0 = rB0a + rB0b, rB1 = rB1a + rB1b;
      // activations (uniform branch on w): w=0 -> sigm,sigm (i,f); w=1 -> tanh,sigm (g,o)
      float a0A, a1A, a0B, a1B;
      if (w == 0) {
        a0A = sigm(rA0); a1A = sigm(rA1);
        a0B = sigm(rB0); a1B = sigm(rB1);
      } else {
        a0A = tanhx(rA0); a1A = sigm(rA1);
        a0B = tanhx(rB0); a1B = sigm(rB1);
      }
      if (act_l) {
        actx[w][0][uc] = make_float2(a0A, a1A);
        actx[w][1][uc] = make_float2(a0B, a1B);
      }
      __syncthreads();
      if (act_l) {
        float2 other = actx[w ^ 1][w][uc];  // wave0: chainA's (g,o); wave1: chainB's (i,f)
        float myv0 = w ? a0B : a0A;         // wave0: iA ; wave1: gB
        float myv1 = w ? a1B : a1A;         // wave0: fA ; wave1: oB
        float iG = w ? other.x : myv0;
        float fG = w ? other.y : myv1;
        float gG = w ? myv0 : other.x;
        float oG = w ? myv1 : other.y;
        c = fG * c + iG * gG;
        float hn = oG * tanhx(c);
        ((_Float16*)&hbuf[w][par ^ 1][0])[u] = (_Float16)hn;
        float mv = hasMask ? mva[j] : 1.f;
        hs8[j] = f2bf(hn * mv);
      }
      __syncthreads();
    }
    if (act_l) {
      int t0 = 8 * g8;
#pragma unroll
      for (int j = 0; j < 8; ++j)
        outp[(size_t)(t0 + j) * 128 + u] = hs8[j];
    }
  }
}

// ---------------- attention (per timestep s) ----------------
__global__ __launch_bounds__(256) void attn_kernel(
    const bf16t* __restrict__ enc1, const bf16t* __restrict__ enc2,
    const float* __restrict__ m1, const float* __restrict__ m2,
    bf16t* __restrict__ d1b, bf16t* __restrict__ d2b) {
  const int s = blockIdx.x;
  const int tid = threadIdx.x;
  __shared__ __align__(16) float E1[BB][DD];
  __shared__ __align__(16) float E2[BB + 1][DD];
  __shared__ __align__(16) float Ah[64][APAD];
  __shared__ float mk1[BB], mk2[BB];
  __shared__ float rden[64];

  for (int idx = tid; idx < BB * 50; idx += 256) {
    int i = idx / 50, dp = idx - i * 50;
    float2 v1 = ldpair(enc1 + ((size_t)i * SQ + s) * 128 + 2 * dp);
    E1[i][2 * dp] = v1.x;
    E1[i][2 * dp + 1] = v1.y;
    float2 v2 = ldpair(enc2 + ((size_t)i * SQ + s) * 128 + 2 * dp);
    E2[i][2 * dp] = v2.x;
    E2[i][2 * dp + 1] = v2.y;
  }
  if (tid < BB) {
    mk1[tid] = m1[tid * SQ + s];
    mk2[tid] = m2[tid * SQ + s];
  }
  __syncthreads();

  const int ti = tid >> 4, tjj = tid & 15;
  const int xj = tid & 127;
  const int xd0 = (tid >> 7) * 50;
  float N[50];
#pragma unroll
  for (int q = 0; q < 50; ++q) N[q] = 0.f;
  float Dacc = 0.f, M = -1e30f;

  for (int half = 0; half < 2; ++half) {
    const int r0 = half * 64;
    float acc[4][8];
#pragma unroll
    for (int ii = 0; ii < 4; ++ii)
#pragma unroll
      for (int jj = 0; jj < 8; ++jj) acc[ii][jj] = 0.f;
    for (int k = 0; k < DD; k += 4) {
      float4 a4[4], b4[8];
#pragma unroll
      for (int ii = 0; ii < 4; ++ii)
        a4[ii] = *(const float4*)&E1[r0 + 4 * ti + ii][k];
#pragma unroll
      for (int jj = 0; jj < 8; ++jj)
        b4[jj] = *(const float4*)&E2[tjj + 16 * jj][k];
#pragma unroll
      for (int ii = 0; ii < 4; ++ii)
#pragma unroll
        for (int jj = 0; jj < 8; ++jj)
          acc[ii][jj] += a4[ii].x * b4[jj].x + a4[ii].y * b4[jj].y +
                         a4[ii].z * b4[jj].z + a4[ii].w * b4[jj].w;
    }
#pragma unroll
    for (int ii = 0; ii < 4; ++ii)
#pragma unroll
      for (int jj = 0; jj < 8; ++jj)
        Ah[4 * ti + ii][tjj + 16 * jj] = acc[ii][jj];
    __syncthreads();

    {
      float lm = M;
      for (int i = 0; i < 64; ++i) lm = fmaxf(lm, Ah[i][xj]);
      float scale = __expf(M - lm);
      Dacc *= scale;
#pragma unroll
      for (int q = 0; q < 50; ++q) N[q] *= scale;
      for (int i = 0; i < 64; ++i) {
        float p = __expf(Ah[i][xj] - lm) * mk1[r0 + i];
        Dacc += p;
        const float2* e1p = (const float2*)&E1[r0 + i][xd0];
#pragma unroll
        for (int q = 0; q < 25; ++q) {
          float2 ev = e1p[q];
          N[2 * q] += p * ev.x;
          N[2 * q + 1] += p * ev.y;
        }
      }
      M = lm;
    }
    __syncthreads();

    {
      int row = tid >> 2, seg = tid & 3;
      float mx = -1e30f;
      for (int q = 0; q < 32; ++q) mx = fmaxf(mx, Ah[row][seg + 4 * q]);
      mx = fmaxf(mx, __shfl_xor(mx, 1));
      mx = fmaxf(mx, __shfl_xor(mx, 2));
      float sm = 0.f;
      for (int q = 0; q < 32; ++q) {
        int jc = seg + 4 * q;
        float p = __expf(Ah[row][jc] - mx) * mk2[jc];
        Ah[row][jc] = p;
        sm += p;
      }
      sm += __shfl_xor(sm, 1);
      sm += __shfl_xor(sm, 2);
      if (seg == 0) rden[row] = sm + 1e-8f;
    }
    __syncthreads();

    {
      float o[4][8];
#pragma unroll
      for (int ii = 0; ii < 4; ++ii)
#pragma unroll
        for (int jj = 0; jj < 8; ++jj) o[ii][jj] = 0.f;
      for (int jb = 0; jb < BB; ++jb) {
        float pv[4], ev[8];
#pragma unroll
        for (int ii = 0; ii < 4; ++ii) pv[ii] = Ah[4 * ti + ii][jb];
#pragma unroll
        for (int jj = 0; jj < 8; ++jj) ev[jj] = E2[jb][tjj + 16 * jj];
#pragma unroll
        for (int ii = 0; ii < 4; ++ii)
#pragma unroll
          for (int jj = 0; jj < 8; ++jj) o[ii][jj] += pv[ii] * ev[jj];
      }
#pragma unroll
      for (int ii = 0; ii < 4; ++ii) {
        int i = r0 + 4 * ti + ii;
        float inv = 1.f / rden[4 * ti + ii];
#pragma unroll
        for (int jj = 0; jj < 8; ++jj) {
          int d = tjj + 16 * jj;
          float val = (d < DD) ? o[ii][jj] * inv : 0.f;
          d1b[((size_t)i * SQ + s) * 128 + d] = f2bf(val);
        }
      }
    }
    __syncthreads();
  }
  float invD = 1.f / (Dacc + 1e-8f);
#pragma unroll
  for (int q = 0; q < 50; ++q)
    d2b[((size_t)xj * SQ + s) * 128 + xd0 + q] = f2bf(N[q] * invD);
  if (xd0 == 50) {
#pragma unroll
    for (int q = 0; q < 28; ++q)
      d2b[((size_t)xj * SQ + s) * 128 + 100 + q] = 0;
  }
}

// ---------------- masked pooling (cmp stride 128) ----------------
__global__ __launch_bounds__(128) void pool_kernel(
    const bf16t* __restrict__ cmp1, const bf16t* __restrict__ cmp2,
    const float* __restrict__ m1, const float* __restrict__ m2,
    float* __restrict__ pooled) {
  int b = blockIdx.x & 127, inp = blockIdx.x >> 7;
  const bf16t* C = (inp ? cmp2 : cmp1) + (size_t)b * SQ * 128;
  const float* M = (inp ? m2 : m1) + b * SQ;
  int f = threadIdx.x;
  float ms = 0.f;
  for (int s = f; s < SQ; s += 128) ms += M[s];
  __shared__ float red[128];
  red[f] = ms;
  __syncthreads();
  for (int o = 64; o > 0; o >>= 1) {
    if (f < o) red[f] += red[f + o];
    __syncthreads();
  }
  float msum = red[0];
  if (f < 100) {
    float sm = 0.f, mx = -1e30f;
    for (int s = 0; s < SQ; ++s) {
      float v = bf2f(C[(size_t)s * 128 + f]) * M[s];
      sm += v;
      mx = fmaxf(mx, v);
    }
    pooled[b * 400 + inp * 200 + f] = sm / msum;
    pooled[b * 400 + inp * 200 + 100 + f] = mx;
  }
}

// ---------------- final MLP + softmax ----------------
__global__ __launch_bounds__(128) void final_kernel(
    const float* __restrict__ pooled, const float* __restrict__ W1,
    const float* __restrict__ b1, const float* __restrict__ W2,
    const float* __restrict__ b2, float* __restrict__ out) {
  int b = blockIdx.x;
  int j = threadIdx.x;
  __shared__ float pr[400];
  __shared__ float h[100];
  for (int idx = j; idx < 400; idx += 128) pr[idx] = pooled[b * 400 + idx];
  __syncthreads();
  if (j < 100) {
    float a = b1[j];
    for (int k = 0; k < 400; ++k) a += pr[k] * W1[k * 100 + j];
    h[j] = tanhx(a);
  }
  __syncthreads();
  if (j == 0) {
    float l0 = b2[0], l1 = b2[1];
    for (int k = 0; k < 100; ++k) {
      l0 += h[k] * W2[k * 2];
      l1 += h[k] * W2[k * 2 + 1];
    }
    float mx = fmaxf(l0, l1);
    float e0 = __expf(l0 - mx), e1 = __expf(l1 - mx);
    float inv = 1.f / (e0 + e1);
    out[b * 2] = e0 * inv;
    out[b * 2 + 1] = e1 * inv;
  }
}

extern "C" void kernel_launch(void* const* d_in, const int* in_sizes, int n_in,
                              void* d_out, int out_size, void* d_ws, size_t ws_size,
                              hipStream_t stream) {
  const int* x1 = (const int*)d_in[0];
  const int* x2 = (const int*)d_in[1];
  const float* emb = (const float*)d_in[2];
  const float* b1f_Wx = (const float*)d_in[3];
  const float* b1f_Wh = (const float*)d_in[4];
  const float* b1f_b = (const float*)d_in[5];
  const float* b1b_Wx = (const float*)d_in[6];
  const float* b1b_Wh = (const float*)d_in[7];
  const float* b1b_b = (const float*)d_in[8];
  const float* dense_W = (const float*)d_in[9];
  const float* dense_b = (const float*)d_in[10];
  const float* b2f_Wx = (const float*)d_in[11];
  const float* b2f_Wh = (const float*)d_in[12];
  const float* b2f_b = (const float*)d_in[13];
  const float* b2b_Wx = (const float*)d_in[14];
  const float* b2b_Wh = (const float*)d_in[15];
  const float* b2b_b = (const float*)d_in[16];
  const float* dense1_W = (const float*)d_in[17];
  const float* dense1_b = (const float*)d_in[18];
  const float* out_W = (const float*)d_in[19];
  const float* out_b = (const float*)d_in[20];
  float* out = (float*)d_out;

  // ---- workspace layout (~173 MB) ----
  char* base = (char*)d_ws;
  bf16t* xz = (bf16t*)base;               // xzT [4][128][200][512]
  bf16t* d1b = (bf16t*)base;
  bf16t* d2b = d1b + (size_t)TOKN * 128;
  char* r1 = base + (size_t)4 * TOKN * 200 * 2;
  bf16t* enc1 = (bf16t*)r1;
  bf16t* enc2 = enc1 + (size_t)TOKN * 128;
  bf16t* e1b = (bf16t*)r1;
  bf16t* e2b = e1b + (size_t)TOKN * 64;
  char* r2 = r1 + (size_t)2 * TOKN * 128 * 2;
  bf16t* map1 = (bf16t*)r2;
  bf16t* map2 = map1 + (size_t)TOKN * 128;
  char* r3 = r2 + (size_t)2 * TOKN * 128 * 2;
  float* m1 = (float*)r3;
  float* m2 = m1 + TOKN;
  float* pooled = m2 + TOKN;
  bf16t* w1T = (bf16t*)(r3 + ((size_t)2 * TOKN + 128 * 400) * 4);
  bf16t* w2T = w1T + 2 * 208 * 64;
  bf16t* wdT = w2T + 2 * 208 * 128;
  unsigned* whP = (unsigned*)(wdT + 128 * 384);  // [4][25][200] packed half2
  bf16t* cmp1 = enc1;
  bf16t* cmp2 = enc2;
  (void)in_sizes; (void)n_in; (void)out_size; (void)ws_size;

  embed_kernel<<<dim3(TOKN * 64 / 256, 2), 256, 0, stream>>>(
      x1, x2, emb, e1b, e2b, m1, m2);
  wprep_kernel<<<dim3(208, 4), 256, 0, stream>>>(
      b1f_Wx, b1b_Wx, b2f_Wx, b2b_Wx, dense_W,
      b1f_Wh, b1b_Wh, b2f_Wh, b2b_Wh, w1T, w2T, wdT, whP);
  xz_mfma<64><<<dim3(TOKN / 64, 4), 256, 0, stream>>>(
      e1b, e2b, w1T, b1f_b, b1b_b, xz);
  padzero_kernel<<<(TOKN * 14 + 255) / 256, 256, 0, stream>>>(
      (unsigned*)enc1, (unsigned*)enc2);
  lstm_scan<<<256, 128, 0, stream>>>(xz, whP, enc1, enc2, m1, m2, 1);
  attn_kernel<<<SQ, 256, 0, stream>>>(enc1, enc2, m1, m2, d1b, d2b);
  dense_mfma<<<dim3(TOKN / 64, 2), 256, 0, stream>>>(
      enc1, enc2, d1b, d2b, wdT, dense_b, map1, map2);
  xz_mfma<128><<<dim3(TOKN / 64, 4), 256, 0, stream>>>(
      map1, map2, w2T, b2f_b, b2b_b, xz);
  lstm_scan<<<256, 128, 0, stream>>>(xz, whP + 2 * 5000, cmp1, cmp2, m1, m2, 0);
  pool_kernel<<<256, 128, 0, stream>>>(cmp1, cmp2, m1, m2, pooled);
  final_kernel<<<128, 128, 0, stream>>>(pooled, dense1_W, dense1_b, out_W, out_b, out);
}

// Round 16
// 1051.967 us; speedup vs baseline: 1.2042x; 1.2042x over previous
//
#include <hip/hip_runtime.h>

#define TOKN 65536   // 128*512
#define SQ 512
#define BB 128
#define DD 100
#define APAD 132

typedef unsigned short bf16t;
typedef __attribute__((ext_vector_type(8))) short bf16x8;
typedef __attribute__((ext_vector_type(4))) float floatx4;
typedef __attribute__((ext_vector_type(2))) _Float16 half2t;

__device__ __forceinline__ float bf2f(bf16t v) {
  unsigned u = ((unsigned)v) << 16;
  return __uint_as_float(u);
}
__device__ __forceinline__ bf16t f2bf(float x) {
  unsigned u = __float_as_uint(x);
  unsigned r = u + 0x7FFFu + ((u >> 16) & 1u);
  return (bf16t)(r >> 16);
}
__device__ __forceinline__ float2 ldpair(const float* p) { return *(const float2*)p; }
__device__ __forceinline__ float2 ldpair(const bf16t* p) {
  unsigned u = *(const unsigned*)p;
  float2 r;
  r.x = __uint_as_float(u << 16);
  r.y = __uint_as_float(u & 0xFFFF0000u);
  return r;
}
__device__ __forceinline__ half2t u2h2(unsigned u) {
  union { unsigned u; half2t h; } x; x.u = u; return x.h;
}

__device__ __forceinline__ float sigm(float x) { return 1.f / (1.f + __expf(-x)); }
__device__ __forceinline__ float tanhx(float x) { return 1.f - 2.f / (1.f + __expf(2.f * x)); }

#if __has_builtin(__builtin_amdgcn_fdot2)
#define DOT2(hu, wu, acc) acc = __builtin_amdgcn_fdot2(u2h2(hu), u2h2(wu), acc, false);
#else
#define DOT2(hu, wu, acc) { half2t hh = u2h2(hu), ww = u2h2(wu); \
  acc = fmaf((float)hh[0], (float)ww[0], acc); \
  acc = fmaf((float)hh[1], (float)ww[1], acc); }
#endif

// ---------------- embedding + mask: e[TOKN][64] bf16 (K-padded) ----------------
__global__ __launch_bounds__(256) void embed_kernel(
    const int* __restrict__ x1, const int* __restrict__ x2,
    const float* __restrict__ emb,
    bf16t* __restrict__ e1, bf16t* __restrict__ e2,
    float* __restrict__ m1, float* __restrict__ m2) {
  const int which = blockIdx.y;
  const int* __restrict__ x = which ? x2 : x1;
  bf16t* __restrict__ e = which ? e2 : e1;
  float* __restrict__ m = which ? m2 : m1;
  int idx = blockIdx.x * 256 + threadIdx.x;  // over TOKN*64
  int t = idx >> 6, d = idx & 63;
  int tok = x[t];
  float mk = (tok != 0) ? 1.f : 0.f;
  float v = (d < 50) ? emb[tok * 50 + d] * mk : 0.f;
  e[idx] = f2bf(v);
  if (d == 0) m[t] = mk;
}

// ---------------- zero K-pad columns 100..127 of enc1/enc2 ----------------
__global__ __launch_bounds__(256) void padzero_kernel(
    unsigned* __restrict__ p1, unsigned* __restrict__ p2) {
  int idx = blockIdx.x * 256 + threadIdx.x;  // TOKN*14 dwords
  if (idx >= TOKN * 14) return;
  int t = idx / 14, d = idx - t * 14;
  p1[(size_t)t * 64 + 50 + d] = 0u;
  p2[(size_t)t * 64 + 50 + d] = 0u;
}

// ---------------- weight prep ----------------
__global__ __launch_bounds__(256) void wprep_kernel(
    const float* __restrict__ w1f, const float* __restrict__ w1b,
    const float* __restrict__ w2f, const float* __restrict__ w2b,
    const float* __restrict__ dW,
    const float* __restrict__ h1f, const float* __restrict__ h1b,
    const float* __restrict__ h2f, const float* __restrict__ h2b,
    bf16t* __restrict__ w1T, bf16t* __restrict__ w2T, bf16t* __restrict__ wdT,
    unsigned* __restrict__ whP) {
  int idx = blockIdx.x * 256 + threadIdx.x;
  int sec = blockIdx.y;
  if (sec == 0) {
    if (idx >= 2 * 208 * 64) return;
    int d = idx / (208 * 64), r = idx % (208 * 64);
    int n = r >> 6, k = r & 63;
    const float* W = d ? w1b : w1f;
    float v = (n < 200 && k < 50) ? W[k * 200 + n] : 0.f;
    w1T[idx] = f2bf(v);
  } else if (sec == 1) {
    if (idx >= 2 * 208 * 128) return;
    int d = idx / (208 * 128), r = idx % (208 * 128);
    int n = r >> 7, k = r & 127;
    const float* W = d ? w2b : w2f;
    float v = (n < 200 && k < 100) ? W[k * 200 + n] : 0.f;
    w2T[idx] = f2bf(v);
  } else if (sec == 2) {
    if (idx >= 128 * 384) return;
    int n = idx / 384, kv = idx % 384;
    int reg = kv >> 7, kk = kv & 127;
    float v = 0.f;
    if (n < 100 && kk < 100) {
      if (reg == 0) v = dW[kk * 100 + n] + dW[(300 + kk) * 100 + n];
      else if (reg == 1) v = dW[(100 + kk) * 100 + n] - dW[(300 + kk) * 100 + n];
      else v = dW[(200 + kk) * 100 + n];
    }
    wdT[idx] = f2bf(v);
  } else {
    if (idx >= 4 * 25 * 200) return;
    int sd = idx / 5000, r = idx % 5000;
    int k2 = r / 200, colx = r % 200;
    const float* W = (sd == 0) ? h1f : (sd == 1) ? h1b : (sd == 2) ? h2f : h2b;
    float v0 = W[(2 * k2) * 200 + colx];
    float v1 = W[(2 * k2 + 1) * 200 + colx];
    union { _Float16 h[2]; unsigned u; } p;
    p.h[0] = (_Float16)v0;
    p.h[1] = (_Float16)v1;
    whP[idx] = p.u;
  }
}

// ---------------- MFMA xz GEMM: xzT[combo][b][200][512] = A@Wx + b ----------------
template <int KP>
__global__ __launch_bounds__(256) void xz_mfma(
    const bf16t* __restrict__ A1, const bf16t* __restrict__ A2,
    const bf16t* __restrict__ WT,
    const float* __restrict__ bf_, const float* __restrict__ bb_,
    bf16t* __restrict__ out) {
  const int combo = blockIdx.y;
  const bf16t* __restrict__ A = (combo < 2) ? A1 : A2;
  const bf16t* __restrict__ W = WT + (size_t)(combo & 1) * 208 * KP;
  const float* __restrict__ bias = (combo & 1) ? bb_ : bf_;
  bf16t* __restrict__ O = out + (size_t)combo * TOKN * 200;
  const int tid = threadIdx.x;
  const int wave = tid >> 6, lane = tid & 63;
  const int m0 = blockIdx.x * 64 + wave * 16;
  const int l15 = lane & 15, quad = lane >> 4;
  floatx4 acc[13];
#pragma unroll
  for (int nt = 0; nt < 13; ++nt) acc[nt] = (floatx4){0.f, 0.f, 0.f, 0.f};
  const bf16t* __restrict__ arow = A + (size_t)(m0 + l15) * KP + quad * 8;
  const bf16t* __restrict__ wb = W + (size_t)l15 * KP + quad * 8;
#pragma unroll
  for (int ks = 0; ks < KP / 32; ++ks) {
    bf16x8 a = *(const bf16x8*)(arow + ks * 32);
#pragma unroll
    for (int nt = 0; nt < 13; ++nt) {
      bf16x8 b = *(const bf16x8*)(wb + (size_t)nt * 16 * KP + ks * 32);
      acc[nt] = __builtin_amdgcn_mfma_f32_16x16x32_bf16(a, b, acc[nt], 0, 0, 0);
    }
  }
  const int crow = m0 + quad * 4;
  const int bidx = crow >> 9;
  const int trow = crow & 511;
#pragma unroll
  for (int nt = 0; nt < 13; ++nt) {
    int n = nt * 16 + l15;
    if (n < 200) {
      float bn = bias[n];
      union { bf16t h[4]; uint2 u2; } pk;
#pragma unroll
      for (int r = 0; r < 4; ++r) pk.h[r] = f2bf(acc[nt][r] + bn);
      *(uint2*)&O[((size_t)bidx * 200 + n) * SQ + trow] = pk.u2;
    }
  }
}

// ---------------- MFMA dense: map = relu([e,d,e*d]@W' + b), out [t][128] ----------------
__global__ __launch_bounds__(256) void dense_mfma(
    const bf16t* __restrict__ enc1, const bf16t* __restrict__ enc2,
    const bf16t* __restrict__ d1b, const bf16t* __restrict__ d2b,
    const bf16t* __restrict__ wdT, const float* __restrict__ bias,
    bf16t* __restrict__ map1, bf16t* __restrict__ map2) {
  const int inp = blockIdx.y;
  const bf16t* __restrict__ E = inp ? enc2 : enc1;
  const bf16t* __restrict__ Db = inp ? d2b : d1b;
  bf16t* __restrict__ O = inp ? map2 : map1;
  const int tid = threadIdx.x;
  const int wave = tid >> 6, lane = tid & 63;
  const int m0 = blockIdx.x * 64 + wave * 16;
  const int l15 = lane & 15, quad = lane >> 4;
  floatx4 acc[8];
#pragma unroll
  for (int nt = 0; nt < 8; ++nt) acc[nt] = (floatx4){0.f, 0.f, 0.f, 0.f};
  const bf16t* __restrict__ erow = E + (size_t)(m0 + l15) * 128 + quad * 8;
  const bf16t* __restrict__ drow = Db + (size_t)(m0 + l15) * 128 + quad * 8;
  const bf16t* __restrict__ wb = wdT + (size_t)l15 * 384 + quad * 8;
#pragma unroll
  for (int ks = 0; ks < 4; ++ks) {
    bf16x8 ae = *(const bf16x8*)(erow + ks * 32);
    bf16x8 ad = *(const bf16x8*)(drow + ks * 32);
    bf16x8 aed;
#pragma unroll
    for (int q = 0; q < 8; ++q) {
      float pe = bf2f((bf16t)ae[q]);
      float pd = bf2f((bf16t)ad[q]);
      aed[q] = (short)f2bf(pe * pd);
    }
#pragma unroll
    for (int nt = 0; nt < 8; ++nt) {
      const bf16t* wn = wb + (size_t)nt * 16 * 384 + ks * 32;
      bf16x8 b0 = *(const bf16x8*)(wn);
      acc[nt] = __builtin_amdgcn_mfma_f32_16x16x32_bf16(ae, b0, acc[nt], 0, 0, 0);
      bf16x8 b1 = *(const bf16x8*)(wn + 128);
      acc[nt] = __builtin_amdgcn_mfma_f32_16x16x32_bf16(ad, b1, acc[nt], 0, 0, 0);
      bf16x8 b2 = *(const bf16x8*)(wn + 256);
      acc[nt] = __builtin_amdgcn_mfma_f32_16x16x32_bf16(aed, b2, acc[nt], 0, 0, 0);
    }
  }
  const int crow = m0 + quad * 4;
#pragma unroll
  for (int nt = 0; nt < 8; ++nt) {
    int n = nt * 16 + l15;
    float bn = (n < 100) ? bias[n] : 0.f;
#pragma unroll
    for (int r = 0; r < 4; ++r) {
      float v = (n < 100) ? fmaxf(acc[nt][r] + bn, 0.f) : 0.f;
      O[(size_t)(crow + r) * 128 + n] = f2bf(v);
    }
  }
}

// ---------------- LSTM scan: ONE WAVE per (scan,batch), unit-per-lane ----------------
// r13 shape, byte-identical (best measured: 254 us/scan, VGPR 108).
__global__ __launch_bounds__(64)
__attribute__((amdgpu_waves_per_eu(1, 2)))
void lstm_scan(
    const bf16t* __restrict__ xzT,      // [4][128][200][512]
    const unsigned* __restrict__ whPL,  // [2][25][200] packed half2
    bf16t* __restrict__ out1, bf16t* __restrict__ out2,
    const float* __restrict__ m1, const float* __restrict__ m2,
    int hasMask) {
  const int blk = blockIdx.x;
  const int scan = blk >> 7;
  const int b = blk & 127;
  const int inp = scan >> 1;
  const int dir = scan & 1;
  const int u = threadIdx.x;
  const bool act_l = (u < 50);
  const int uc = act_l ? u : 0;
  const bf16t* __restrict__ xbase = xzT + ((size_t)scan * 128 + b) * 200 * SQ;
  const bf16t* __restrict__ xi = xbase + (size_t)uc * SQ;
  const bf16t* __restrict__ xf = xbase + (size_t)(50 + uc) * SQ;
  const bf16t* __restrict__ xg = xbase + (size_t)(100 + uc) * SQ;
  const bf16t* __restrict__ xo = xbase + (size_t)(150 + uc) * SQ;
  bf16t* __restrict__ outp = (inp ? out2 : out1) + (size_t)b * SQ * 128 + dir * 50;
  const float* __restrict__ mk = (inp ? m2 : m1) + b * SQ;
  __shared__ __align__(16) unsigned hbuf[2][32];  // packed f16 h, dbl-buffered

  const unsigned* __restrict__ wsrc = whPL + dir * 5000;
  unsigned wgt[4][25];
#pragma unroll
  for (int gg = 0; gg < 4; ++gg)
#pragma unroll
    for (int k2 = 0; k2 < 25; ++k2)
      wgt[gg][k2] = wsrc[k2 * 200 + gg * 50 + uc];
#pragma unroll
  for (int gg = 0; gg < 4; ++gg)
#pragma unroll
    for (int k2 = 0; k2 < 25; ++k2)
      asm volatile("" : "+v"(wgt[gg][k2]));

  ((unsigned*)hbuf)[u] = 0;  // u<64 covers both parity buffers
  float c = 0.f;
  const float4* mk4 = (const float4*)mk;

  uint4 zc0, zc1, zc2, zc3, zn0, zn1, zn2, zn3;
  {
    int r0 = dir ? (SQ - 8) : 0;
    int r1 = dir ? (SQ - 16) : 8;
    zc0 = *(const uint4*)(xi + r0); zn0 = *(const uint4*)(xi + r1);
    zc1 = *(const uint4*)(xf + r0); zn1 = *(const uint4*)(xf + r1);
    zc2 = *(const uint4*)(xg + r0); zn2 = *(const uint4*)(xg + r1);
    zc3 = *(const uint4*)(xo + r0); zn3 = *(const uint4*)(xo + r1);
  }

  for (int g8 = 0; g8 < SQ / 8; ++g8) {
    // unpack 4 streams x 8 steps, honoring direction (uniform branch)
    float zst[4][8];
    {
      uint4 cur[4] = {zc0, zc1, zc2, zc3};
#pragma unroll
      for (int gg = 0; gg < 4; ++gg) {
        unsigned dw[4] = {cur[gg].x, cur[gg].y, cur[gg].z, cur[gg].w};
#pragma unroll
        for (int p = 0; p < 4; ++p) {
          float lo = __uint_as_float(dw[p] << 16);
          float hi = __uint_as_float(dw[p] & 0xFFFF0000u);
          if (dir) { zst[gg][7 - 2 * p] = lo; zst[gg][6 - 2 * p] = hi; }
          else     { zst[gg][2 * p] = lo;     zst[gg][2 * p + 1] = hi; }
        }
      }
    }
    // rotate prefetch
    uint4 zf0 = zn0, zf1 = zn1, zf2 = zn2, zf3 = zn3;
    {
      int gnext = (g8 + 2 < SQ / 8) ? (g8 + 2) : (SQ / 8 - 1);
      int rn = dir ? (SQ - 8 - 8 * gnext) : (8 * gnext);
      zn0 = *(const uint4*)(xi + rn);
      zn1 = *(const uint4*)(xf + rn);
      zn2 = *(const uint4*)(xg + rn);
      zn3 = *(const uint4*)(xo + rn);
    }
    float mva[8];
    if (hasMask) {
      float4 ma = mk4[2 * g8], mb = mk4[2 * g8 + 1];
      mva[0] = ma.x; mva[1] = ma.y; mva[2] = ma.z; mva[3] = ma.w;
      mva[4] = mb.x; mva[5] = mb.y; mva[6] = mb.z; mva[7] = mb.w;
    }
    bf16t hs8[8];
#pragma unroll
    for (int j = 0; j < 8; ++j) {
      const int par = j & 1;
      const uint4* hp = (const uint4*)&hbuf[par][0];
      uint4 q0 = hp[0], q1 = hp[1], q2 = hp[2], q3 = hp[3], q4 = hp[4], q5 = hp[5];
      unsigned qL = hbuf[par][24];
      unsigned hd[25] = {q0.x, q0.y, q0.z, q0.w, q1.x, q1.y, q1.z, q1.w,
                         q2.x, q2.y, q2.z, q2.w, q3.x, q3.y, q3.z, q3.w,
                         q4.x, q4.y, q4.z, q4.w, q5.x, q5.y, q5.z, q5.w, qL};
      float res[4];
#pragma unroll
      for (int gg = 0; gg < 4; ++gg) {
        float a0 = zst[gg][j], a1 = 0.f;
#pragma unroll
        for (int k2 = 0; k2 < 24; k2 += 2) {
          DOT2(hd[k2], wgt[gg][k2], a0)
          DOT2(hd[k2 + 1], wgt[gg][k2 + 1], a1)
        }
        DOT2(hd[24], wgt[gg][24], a0)
        res[gg] = a0 + a1;
      }
      float ai = sigm(res[0]);
      float af = sigm(res[1]);
      float ag = tanhx(res[2]);
      float ao = sigm(res[3]);
      c = af * c + ai * ag;
      float hn = ao * tanhx(c);
      if (act_l) {
        ((_Float16*)&hbuf[par ^ 1][0])[u] = (_Float16)hn;
        float mv = hasMask ? mva[j] : 1.f;
        hs8[j] = f2bf(hn * mv);
      }
    }
    if (act_l) {
      int t0 = 8 * g8;
#pragma unroll
      for (int j = 0; j < 8; ++j)
        outp[(size_t)(t0 + j) * 128 + u] = hs8[j];
    }
    zc0 = zf0; zc1 = zf1; zc2 = zf2; zc3 = zf3;
  }
}

// ---------------- attention (per timestep s) ----------------
// GEMM2 remapped to contiguous column octets: per 4-jb chunk 12x ds_read_b128
// (was 48x ds_read_b32); output packed as one uint4 store per row.
__global__ __launch_bounds__(256) void attn_kernel(
    const bf16t* __restrict__ enc1, const bf16t* __restrict__ enc2,
    const float* __restrict__ m1, const float* __restrict__ m2,
    bf16t* __restrict__ d1b, bf16t* __restrict__ d2b) {
  const int s = blockIdx.x;
  const int tid = threadIdx.x;
  __shared__ __align__(16) float E1[BB][DD];
  __shared__ __align__(16) float E2[BB + 1][DD];
  __shared__ __align__(16) float Ah[64][APAD];
  __shared__ float mk1[BB], mk2[BB];
  __shared__ float rden[64];

  for (int idx = tid; idx < BB * 50; idx += 256) {
    int i = idx / 50, dp = idx - i * 50;
    float2 v1 = ldpair(enc1 + ((size_t)i * SQ + s) * 128 + 2 * dp);
    E1[i][2 * dp] = v1.x;
    E1[i][2 * dp + 1] = v1.y;
    float2 v2 = ldpair(enc2 + ((size_t)i * SQ + s) * 128 + 2 * dp);
    E2[i][2 * dp] = v2.x;
    E2[i][2 * dp + 1] = v2.y;
  }
  if (tid < BB) {
    mk1[tid] = m1[tid * SQ + s];
    mk2[tid] = m2[tid * SQ + s];
  }
  __syncthreads();

  const int ti = tid >> 4, tjj = tid & 15;
  const int xj = tid & 127;
  const int xd0 = (tid >> 7) * 50;
  float N[50];
#pragma unroll
  for (int q = 0; q < 50; ++q) N[q] = 0.f;
  float Dacc = 0.f, M = -1e30f;

  for (int half = 0; half < 2; ++half) {
    const int r0 = half * 64;
    float acc[4][8];
#pragma unroll
    for (int ii = 0; ii < 4; ++ii)
#pragma unroll
      for (int jj = 0; jj < 8; ++jj) acc[ii][jj] = 0.f;
    for (int k = 0; k < DD; k += 4) {
      float4 a4[4], b4[8];
#pragma unroll
      for (int ii = 0; ii < 4; ++ii)
        a4[ii] = *(const float4*)&E1[r0 + 4 * ti + ii][k];
#pragma unroll
      for (int jj = 0; jj < 8; ++jj)
        b4[jj] = *(const float4*)&E2[tjj + 16 * jj][k];
#pragma unroll
      for (int ii = 0; ii < 4; ++ii)
#pragma unroll
        for (int jj = 0; jj < 8; ++jj)
          acc[ii][jj] += a4[ii].x * b4[jj].x + a4[ii].y * b4[jj].y +
                         a4[ii].z * b4[jj].z + a4[ii].w * b4[jj].w;
    }
#pragma unroll
    for (int ii = 0; ii < 4; ++ii)
#pragma unroll
      for (int jj = 0; jj < 8; ++jj)
        Ah[4 * ti + ii][tjj + 16 * jj] = acc[ii][jj];
    __syncthreads();

    {
      float lm = M;
      for (int i = 0; i < 64; ++i) lm = fmaxf(lm, Ah[i][xj]);
      float scale = __expf(M - lm);
      Dacc *= scale;
#pragma unroll
      for (int q = 0; q < 50; ++q) N[q] *= scale;
      for (int i = 0; i < 64; ++i) {
        float p = __expf(Ah[i][xj] - lm) * mk1[r0 + i];
        Dacc += p;
        const float2* e1p = (const float2*)&E1[r0 + i][xd0];
#pragma unroll
        for (int q = 0; q < 25; ++q) {
          float2 ev = e1p[q];
          N[2 * q] += p * ev.x;
          N[2 * q + 1] += p * ev.y;
        }
      }
      M = lm;
    }
    __syncthreads();

    {
      int row = tid >> 2, seg = tid & 3;
      float mx = -1e30f;
      for (int q = 0; q < 32; ++q) mx = fmaxf(mx, Ah[row][seg + 4 * q]);
      mx = fmaxf(mx, __shfl_xor(mx, 1));
      mx = fmaxf(mx, __shfl_xor(mx, 2));
      float sm = 0.f;
      for (int q = 0; q < 32; ++q) {
        int jc = seg + 4 * q;
        float p = __expf(Ah[row][jc] - mx) * mk2[jc];
        Ah[row][jc] = p;
        sm += p;
      }
      sm += __shfl_xor(sm, 1);
      sm += __shfl_xor(sm, 2);
      if (seg == 0) rden[row] = sm + 1e-8f;
    }
    __syncthreads();

    {
      // GEMM2: rows 4*ri..4*ri+3, cols 8*cg..8*cg+7 (contiguous octet)
      const int ri = tid >> 4, cg = tid & 15;
      float o[4][8];
#pragma unroll
      for (int ii = 0; ii < 4; ++ii)
#pragma unroll
        for (int jj = 0; jj < 8; ++jj) o[ii][jj] = 0.f;
      for (int jb = 0; jb < BB; jb += 4) {
        float4 pv[4];
#pragma unroll
        for (int ii = 0; ii < 4; ++ii)
          pv[ii] = *(const float4*)&Ah[4 * ri + ii][jb];
#pragma unroll
        for (int q = 0; q < 4; ++q) {
          float4 e0 = *(const float4*)&E2[jb + q][8 * cg];
          float4 e1v = *(const float4*)&E2[jb + q][8 * cg + 4];
          float ev[8] = {e0.x, e0.y, e0.z, e0.w, e1v.x, e1v.y, e1v.z, e1v.w};
#pragma unroll
          for (int ii = 0; ii < 4; ++ii) {
            float p = (q == 0) ? pv[ii].x : (q == 1) ? pv[ii].y
                     : (q == 2) ? pv[ii].z : pv[ii].w;
#pragma unroll
            for (int jj = 0; jj < 8; ++jj) o[ii][jj] = fmaf(p, ev[jj], o[ii][jj]);
          }
        }
      }
#pragma unroll
      for (int ii = 0; ii < 4; ++ii) {
        int i = r0 + 4 * ri + ii;
        float inv = 1.f / rden[4 * ri + ii];
        union { bf16t h[8]; uint4 u4; } pk;
#pragma unroll
        for (int jj = 0; jj < 8; ++jj) {
          int d = 8 * cg + jj;
          pk.h[jj] = (d < DD) ? f2bf(o[ii][jj] * inv) : (bf16t)0;
        }
        *(uint4*)&d1b[((size_t)i * SQ + s) * 128 + 8 * cg] = pk.u4;
      }
    }
    __syncthreads();
  }
  float invD = 1.f / (Dacc + 1e-8f);
#pragma unroll
  for (int q = 0; q < 50; ++q)
    d2b[((size_t)xj * SQ + s) * 128 + xd0 + q] = f2bf(N[q] * invD);
  if (xd0 == 50) {
#pragma unroll
    for (int q = 0; q < 28; ++q)
      d2b[((size_t)xj * SQ + s) * 128 + 100 + q] = 0;
  }
}

// ---------------- masked pooling (cmp stride 128) ----------------
__global__ __launch_bounds__(128) void pool_kernel(
    const bf16t* __restrict__ cmp1, const bf16t* __restrict__ cmp2,
    const float* __restrict__ m1, const float* __restrict__ m2,
    float* __restrict__ pooled) {
  int b = blockIdx.x & 127, inp = blockIdx.x >> 7;
  const bf16t* C = (inp ? cmp2 : cmp1) + (size_t)b * SQ * 128;
  const float* M = (inp ? m2 : m1) + b * SQ;
  int f = threadIdx.x;
  float ms = 0.f;
  for (int s = f; s < SQ; s += 128) ms += M[s];
  __shared__ float red[128];
  red[f] = ms;
  __syncthreads();
  for (int o = 64; o > 0; o >>= 1) {
    if (f < o) red[f] += red[f + o];
    __syncthreads();
  }
  float msum = red[0];
  if (f < 100) {
    float sm = 0.f, mx = -1e30f;
    for (int s = 0; s < SQ; ++s) {
      float v = bf2f(C[(size_t)s * 128 + f]) * M[s];
      sm += v;
      mx = fmaxf(mx, v);
    }
    pooled[b * 400 + inp * 200 + f] = sm / msum;
    pooled[b * 400 + inp * 200 + 100 + f] = mx;
  }
}

// ---------------- final MLP + softmax ----------------
__global__ __launch_bounds__(128) void final_kernel(
    const float* __restrict__ pooled, const float* __restrict__ W1,
    const float* __restrict__ b1, const float* __restrict__ W2,
    const float* __restrict__ b2, float* __restrict__ out) {
  int b = blockIdx.x;
  int j = threadIdx.x;
  __shared__ float pr[400];
  __shared__ float h[100];
  for (int idx = j; idx < 400; idx += 128) pr[idx] = pooled[b * 400 + idx];
  __syncthreads();
  if (j < 100) {
    float a = b1[j];
    for (int k = 0; k < 400; ++k) a += pr[k] * W1[k * 100 + j];
    h[j] = tanhx(a);
  }
  __syncthreads();
  if (j == 0) {
    float l0 = b2[0], l1 = b2[1];
    for (int k = 0; k < 100; ++k) {
      l0 += h[k] * W2[k * 2];
      l1 += h[k] * W2[k * 2 + 1];
    }
    float mx = fmaxf(l0, l1);
    float e0 = __expf(l0 - mx), e1 = __expf(l1 - mx);
    float inv = 1.f / (e0 + e1);
    out[b * 2] = e0 * inv;
    out[b * 2 + 1] = e1 * inv;
  }
}

extern "C" void kernel_launch(void* const* d_in, const int* in_sizes, int n_in,
                              void* d_out, int out_size, void* d_ws, size_t ws_size,
                              hipStream_t stream) {
  const int* x1 = (const int*)d_in[0];
  const int* x2 = (const int*)d_in[1];
  const float* emb = (const float*)d_in[2];
  const float* b1f_Wx = (const float*)d_in[3];
  const float* b1f_Wh = (const float*)d_in[4];
  const float* b1f_b = (const float*)d_in[5];
  const float* b1b_Wx = (const float*)d_in[6];
  const float* b1b_Wh = (const float*)d_in[7];
  const float* b1b_b = (const float*)d_in[8];
  const float* dense_W = (const float*)d_in[9];
  const float* dense_b = (const float*)d_in[10];
  const float* b2f_Wx = (const float*)d_in[11];
  const float* b2f_Wh = (const float*)d_in[12];
  const float* b2f_b = (const float*)d_in[13];
  const float* b2b_Wx = (const float*)d_in[14];
  const float* b2b_Wh = (const float*)d_in[15];
  const float* b2b_b = (const float*)d_in[16];
  const float* dense1_W = (const float*)d_in[17];
  const float* dense1_b = (const float*)d_in[18];
  const float* out_W = (const float*)d_in[19];
  const float* out_b = (const float*)d_in[20];
  float* out = (float*)d_out;

  // ---- workspace layout (~173 MB) ----
  char* base = (char*)d_ws;
  bf16t* xz = (bf16t*)base;               // xzT [4][128][200][512]
  bf16t* d1b = (bf16t*)base;
  bf16t* d2b = d1b + (size_t)TOKN * 128;
  char* r1 = base + (size_t)4 * TOKN * 200 * 2;
  bf16t* enc1 = (bf16t*)r1;
  bf16t* enc2 = enc1 + (size_t)TOKN * 128;
  bf16t* e1b = (bf16t*)r1;
  bf16t* e2b = e1b + (size_t)TOKN * 64;
  char* r2 = r1 + (size_t)2 * TOKN * 128 * 2;
  bf16t* map1 = (bf16t*)r2;
  bf16t* map2 = map1 + (size_t)TOKN * 128;
  char* r3 = r2 + (size_t)2 * TOKN * 128 * 2;
  float* m1 = (float*)r3;
  float* m2 = m1 + TOKN;
  float* pooled = m2 + TOKN;
  bf16t* w1T = (bf16t*)(r3 + ((size_t)2 * TOKN + 128 * 400) * 4);
  bf16t* w2T = w1T + 2 * 208 * 64;
  bf16t* wdT = w2T + 2 * 208 * 128;
  unsigned* whP = (unsigned*)(wdT + 128 * 384);  // [4][25][200] packed half2
  bf16t* cmp1 = enc1;
  bf16t* cmp2 = enc2;
  (void)in_sizes; (void)n_in; (void)out_size; (void)ws_size;

  embed_kernel<<<dim3(TOKN * 64 / 256, 2), 256, 0, stream>>>(
      x1, x2, emb, e1b, e2b, m1, m2);
  wprep_kernel<<<dim3(208, 4), 256, 0, stream>>>(
      b1f_Wx, b1b_Wx, b2f_Wx, b2b_Wx, dense_W,
      b1f_Wh, b1b_Wh, b2f_Wh, b2b_Wh, w1T, w2T, wdT, whP);
  xz_mfma<64><<<dim3(TOKN / 64, 4), 256, 0, stream>>>(
      e1b, e2b, w1T, b1f_b, b1b_b, xz);
  padzero_kernel<<<(TOKN * 14 + 255) / 256, 256, 0, stream>>>(
      (unsigned*)enc1, (unsigned*)enc2);
  lstm_scan<<<512, 64, 0, stream>>>(xz, whP, enc1, enc2, m1, m2, 1);
  attn_kernel<<<SQ, 256, 0, stream>>>(enc1, enc2, m1, m2, d1b, d2b);
  dense_mfma<<<dim3(TOKN / 64, 2), 256, 0, stream>>>(
      enc1, enc2, d1b, d2b, wdT, dense_b, map1, map2);
  xz_mfma<128><<<dim3(TOKN / 64, 4), 256, 0, stream>>>(
      map1, map2, w2T, b2f_b, b2b_b, xz);
  lstm_scan<<<512, 64, 0, stream>>>(xz, whP + 2 * 5000, cmp1, cmp2, m1, m2, 0);
  pool_kernel<<<256, 128, 0, stream>>>(cmp1, cmp2, m1, m2, pooled);
  final_kernel<<<128, 128, 0, stream>>>(pooled, dense1_W, dense1_b, out_W, out_b, out);
}

// Round 17
// 1040.306 us; speedup vs baseline: 1.2177x; 1.0112x over previous
//
#include <hip/hip_runtime.h>

#define TOKN 65536   // 128*512
#define SQ 512
#define BB 128
#define DD 100
#define APAD 132

typedef unsigned short bf16t;
typedef __attribute__((ext_vector_type(8))) short bf16x8;
typedef __attribute__((ext_vector_type(4))) float floatx4;
typedef __attribute__((ext_vector_type(2))) _Float16 half2t;

__device__ __forceinline__ float bf2f(bf16t v) {
  unsigned u = ((unsigned)v) << 16;
  return __uint_as_float(u);
}
__device__ __forceinline__ bf16t f2bf(float x) {
  unsigned u = __float_as_uint(x);
  unsigned r = u + 0x7FFFu + ((u >> 16) & 1u);
  return (bf16t)(r >> 16);
}
__device__ __forceinline__ float2 ldpair(const float* p) { return *(const float2*)p; }
__device__ __forceinline__ float2 ldpair(const bf16t* p) {
  unsigned u = *(const unsigned*)p;
  float2 r;
  r.x = __uint_as_float(u << 16);
  r.y = __uint_as_float(u & 0xFFFF0000u);
  return r;
}
__device__ __forceinline__ half2t u2h2(unsigned u) {
  union { unsigned u; half2t h; } x; x.u = u; return x.h;
}
__device__ __forceinline__ unsigned h2u(half2t h) {
  union { half2t h; unsigned u; } x; x.h = h; return x.u;
}
__device__ __forceinline__ half2t f2h2(float a) {
  half2t h; h[0] = (_Float16)a; h[1] = (_Float16)a; return h;
}

__device__ __forceinline__ float sigm(float x) { return 1.f / (1.f + __expf(-x)); }
__device__ __forceinline__ float tanhx(float x) { return 1.f - 2.f / (1.f + __expf(2.f * x)); }

#if __has_builtin(__builtin_amdgcn_fdot2)
#define DOT2(hu, wu, acc) acc = __builtin_amdgcn_fdot2(u2h2(hu), u2h2(wu), acc, false);
#else
#define DOT2(hu, wu, acc) { half2t hh = u2h2(hu), ww = u2h2(wu); \
  acc = fmaf((float)hh[0], (float)ww[0], acc); \
  acc = fmaf((float)hh[1], (float)ww[1], acc); }
#endif

// ---------------- embedding + mask: e[TOKN][64] bf16 (K-padded) ----------------
__global__ __launch_bounds__(256) void embed_kernel(
    const int* __restrict__ x1, const int* __restrict__ x2,
    const float* __restrict__ emb,
    bf16t* __restrict__ e1, bf16t* __restrict__ e2,
    float* __restrict__ m1, float* __restrict__ m2) {
  const int which = blockIdx.y;
  const int* __restrict__ x = which ? x2 : x1;
  bf16t* __restrict__ e = which ? e2 : e1;
  float* __restrict__ m = which ? m2 : m1;
  int idx = blockIdx.x * 256 + threadIdx.x;  // over TOKN*64
  int t = idx >> 6, d = idx & 63;
  int tok = x[t];
  float mk = (tok != 0) ? 1.f : 0.f;
  float v = (d < 50) ? emb[tok * 50 + d] * mk : 0.f;
  e[idx] = f2bf(v);
  if (d == 0) m[t] = mk;
}

// ---------------- zero K-pad columns 100..127 of enc1/enc2 ----------------
__global__ __launch_bounds__(256) void padzero_kernel(
    unsigned* __restrict__ p1, unsigned* __restrict__ p2) {
  int idx = blockIdx.x * 256 + threadIdx.x;  // TOKN*14 dwords
  if (idx >= TOKN * 14) return;
  int t = idx / 14, d = idx - t * 14;
  p1[(size_t)t * 64 + 50 + d] = 0u;
  p2[(size_t)t * 64 + 50 + d] = 0u;
}

// ---------------- weight prep ----------------
__global__ __launch_bounds__(256) void wprep_kernel(
    const float* __restrict__ w1f, const float* __restrict__ w1b,
    const float* __restrict__ w2f, const float* __restrict__ w2b,
    const float* __restrict__ dW,
    const float* __restrict__ h1f, const float* __restrict__ h1b,
    const float* __restrict__ h2f, const float* __restrict__ h2b,
    bf16t* __restrict__ w1T, bf16t* __restrict__ w2T, bf16t* __restrict__ wdT,
    unsigned* __restrict__ whP) {
  int idx = blockIdx.x * 256 + threadIdx.x;
  int sec = blockIdx.y;
  if (sec == 0) {
    if (idx >= 2 * 208 * 64) return;
    int d = idx / (208 * 64), r = idx % (208 * 64);
    int n = r >> 6, k = r & 63;
    const float* W = d ? w1b : w1f;
    float v = (n < 200 && k < 50) ? W[k * 200 + n] : 0.f;
    w1T[idx] = f2bf(v);
  } else if (sec == 1) {
    if (idx >= 2 * 208 * 128) return;
    int d = idx / (208 * 128), r = idx % (208 * 128);
    int n = r >> 7, k = r & 127;
    const float* W = d ? w2b : w2f;
    float v = (n < 200 && k < 100) ? W[k * 200 + n] : 0.f;
    w2T[idx] = f2bf(v);
  } else if (sec == 2) {
    if (idx >= 128 * 384) return;
    int n = idx / 384, kv = idx % 384;
    int reg = kv >> 7, kk = kv & 127;
    float v = 0.f;
    if (n < 100 && kk < 100) {
      if (reg == 0) v = dW[kk * 100 + n] + dW[(300 + kk) * 100 + n];
      else if (reg == 1) v = dW[(100 + kk) * 100 + n] - dW[(300 + kk) * 100 + n];
      else v = dW[(200 + kk) * 100 + n];
    }
    wdT[idx] = f2bf(v);
  } else {
    if (idx >= 4 * 25 * 200) return;
    int sd = idx / 5000, r = idx % 5000;
    int k2 = r / 200, colx = r % 200;
    const float* W = (sd == 0) ? h1f : (sd == 1) ? h1b : (sd == 2) ? h2f : h2b;
    float v0 = W[(2 * k2) * 200 + colx];
    float v1 = W[(2 * k2 + 1) * 200 + colx];
    union { _Float16 h[2]; unsigned u; } p;
    p.h[0] = (_Float16)v0;
    p.h[1] = (_Float16)v1;
    whP[idx] = p.u;
  }
}

// ---------------- MFMA xz GEMM: xzT[combo][b][200][512] = A@Wx + b ----------------
template <int KP>
__global__ __launch_bounds__(256) void xz_mfma(
    const bf16t* __restrict__ A1, const bf16t* __restrict__ A2,
    const bf16t* __restrict__ WT,
    const float* __restrict__ bf_, const float* __restrict__ bb_,
    bf16t* __restrict__ out) {
  const int combo = blockIdx.y;
  const bf16t* __restrict__ A = (combo < 2) ? A1 : A2;
  const bf16t* __restrict__ W = WT + (size_t)(combo & 1) * 208 * KP;
  const float* __restrict__ bias = (combo & 1) ? bb_ : bf_;
  bf16t* __restrict__ O = out + (size_t)combo * TOKN * 200;
  const int tid = threadIdx.x;
  const int wave = tid >> 6, lane = tid & 63;
  const int m0 = blockIdx.x * 64 + wave * 16;
  const int l15 = lane & 15, quad = lane >> 4;
  floatx4 acc[13];
#pragma unroll
  for (int nt = 0; nt < 13; ++nt) acc[nt] = (floatx4){0.f, 0.f, 0.f, 0.f};
  const bf16t* __restrict__ arow = A + (size_t)(m0 + l15) * KP + quad * 8;
  const bf16t* __restrict__ wb = W + (size_t)l15 * KP + quad * 8;
#pragma unroll
  for (int ks = 0; ks < KP / 32; ++ks) {
    bf16x8 a = *(const bf16x8*)(arow + ks * 32);
#pragma unroll
    for (int nt = 0; nt < 13; ++nt) {
      bf16x8 b = *(const bf16x8*)(wb + (size_t)nt * 16 * KP + ks * 32);
      acc[nt] = __builtin_amdgcn_mfma_f32_16x16x32_bf16(a, b, acc[nt], 0, 0, 0);
    }
  }
  const int crow = m0 + quad * 4;
  const int bidx = crow >> 9;
  const int trow = crow & 511;
#pragma unroll
  for (int nt = 0; nt < 13; ++nt) {
    int n = nt * 16 + l15;
    if (n < 200) {
      float bn = bias[n];
      union { bf16t h[4]; uint2 u2; } pk;
#pragma unroll
      for (int r = 0; r < 4; ++r) pk.h[r] = f2bf(acc[nt][r] + bn);
      *(uint2*)&O[((size_t)bidx * 200 + n) * SQ + trow] = pk.u2;
    }
  }
}

// ---------------- MFMA dense: map = relu([e,d,e*d]@W' + b), out [t][128] ----------------
__global__ __launch_bounds__(256) void dense_mfma(
    const bf16t* __restrict__ enc1, const bf16t* __restrict__ enc2,
    const bf16t* __restrict__ d1b, const bf16t* __restrict__ d2b,
    const bf16t* __restrict__ wdT, const float* __restrict__ bias,
    bf16t* __restrict__ map1, bf16t* __restrict__ map2) {
  const int inp = blockIdx.y;
  const bf16t* __restrict__ E = inp ? enc2 : enc1;
  const bf16t* __restrict__ Db = inp ? d2b : d1b;
  bf16t* __restrict__ O = inp ? map2 : map1;
  const int tid = threadIdx.x;
  const int wave = tid >> 6, lane = tid & 63;
  const int m0 = blockIdx.x * 64 + wave * 16;
  const int l15 = lane & 15, quad = lane >> 4;
  floatx4 acc[8];
#pragma unroll
  for (int nt = 0; nt < 8; ++nt) acc[nt] = (floatx4){0.f, 0.f, 0.f, 0.f};
  const bf16t* __restrict__ erow = E + (size_t)(m0 + l15) * 128 + quad * 8;
  const bf16t* __restrict__ drow = Db + (size_t)(m0 + l15) * 128 + quad * 8;
  const bf16t* __restrict__ wb = wdT + (size_t)l15 * 384 + quad * 8;
#pragma unroll
  for (int ks = 0; ks < 4; ++ks) {
    bf16x8 ae = *(const bf16x8*)(erow + ks * 32);
    bf16x8 ad = *(const bf16x8*)(drow + ks * 32);
    bf16x8 aed;
#pragma unroll
    for (int q = 0; q < 8; ++q) {
      float pe = bf2f((bf16t)ae[q]);
      float pd = bf2f((bf16t)ad[q]);
      aed[q] = (short)f2bf(pe * pd);
    }
#pragma unroll
    for (int nt = 0; nt < 8; ++nt) {
      const bf16t* wn = wb + (size_t)nt * 16 * 384 + ks * 32;
      bf16x8 b0 = *(const bf16x8*)(wn);
      acc[nt] = __builtin_amdgcn_mfma_f32_16x16x32_bf16(ae, b0, acc[nt], 0, 0, 0);
      bf16x8 b1 = *(const bf16x8*)(wn + 128);
      acc[nt] = __builtin_amdgcn_mfma_f32_16x16x32_bf16(ad, b1, acc[nt], 0, 0, 0);
      bf16x8 b2 = *(const bf16x8*)(wn + 256);
      acc[nt] = __builtin_amdgcn_mfma_f32_16x16x32_bf16(aed, b2, acc[nt], 0, 0, 0);
    }
  }
  const int crow = m0 + quad * 4;
#pragma unroll
  for (int nt = 0; nt < 8; ++nt) {
    int n = nt * 16 + l15;
    float bn = (n < 100) ? bias[n] : 0.f;
#pragma unroll
    for (int r = 0; r < 4; ++r) {
      float v = (n < 100) ? fmaxf(acc[nt][r] + bn, 0.f) : 0.f;
      O[(size_t)(crow + r) * 128 + n] = f2bf(v);
    }
  }
}

// ---------------- LSTM scan: ONE WAVE per (scan,batch), unit-per-lane ----------------
// r13 shape, byte-identical (best measured: 254 us/scan, VGPR 108).
__global__ __launch_bounds__(64)
__attribute__((amdgpu_waves_per_eu(1, 2)))
void lstm_scan(
    const bf16t* __restrict__ xzT,      // [4][128][200][512]
    const unsigned* __restrict__ whPL,  // [2][25][200] packed half2
    bf16t* __restrict__ out1, bf16t* __restrict__ out2,
    const float* __restrict__ m1, const float* __restrict__ m2,
    int hasMask) {
  const int blk = blockIdx.x;
  const int scan = blk >> 7;
  const int b = blk & 127;
  const int inp = scan >> 1;
  const int dir = scan & 1;
  const int u = threadIdx.x;
  const bool act_l = (u < 50);
  const int uc = act_l ? u : 0;
  const bf16t* __restrict__ xbase = xzT + ((size_t)scan * 128 + b) * 200 * SQ;
  const bf16t* __restrict__ xi = xbase + (size_t)uc * SQ;
  const bf16t* __restrict__ xf = xbase + (size_t)(50 + uc) * SQ;
  const bf16t* __restrict__ xg = xbase + (size_t)(100 + uc) * SQ;
  const bf16t* __restrict__ xo = xbase + (size_t)(150 + uc) * SQ;
  bf16t* __restrict__ outp = (inp ? out2 : out1) + (size_t)b * SQ * 128 + dir * 50;
  const float* __restrict__ mk = (inp ? m2 : m1) + b * SQ;
  __shared__ __align__(16) unsigned hbuf[2][32];  // packed f16 h, dbl-buffered

  const unsigned* __restrict__ wsrc = whPL + dir * 5000;
  unsigned wgt[4][25];
#pragma unroll
  for (int gg = 0; gg < 4; ++gg)
#pragma unroll
    for (int k2 = 0; k2 < 25; ++k2)
      wgt[gg][k2] = wsrc[k2 * 200 + gg * 50 + uc];
#pragma unroll
  for (int gg = 0; gg < 4; ++gg)
#pragma unroll
    for (int k2 = 0; k2 < 25; ++k2)
      asm volatile("" : "+v"(wgt[gg][k2]));

  ((unsigned*)hbuf)[u] = 0;  // u<64 covers both parity buffers
  float c = 0.f;
  const float4* mk4 = (const float4*)mk;

  uint4 zc0, zc1, zc2, zc3, zn0, zn1, zn2, zn3;
  {
    int r0 = dir ? (SQ - 8) : 0;
    int r1 = dir ? (SQ - 16) : 8;
    zc0 = *(const uint4*)(xi + r0); zn0 = *(const uint4*)(xi + r1);
    zc1 = *(const uint4*)(xf + r0); zn1 = *(const uint4*)(xf + r1);
    zc2 = *(const uint4*)(xg + r0); zn2 = *(const uint4*)(xg + r1);
    zc3 = *(const uint4*)(xo + r0); zn3 = *(const uint4*)(xo + r1);
  }

  for (int g8 = 0; g8 < SQ / 8; ++g8) {
    // unpack 4 streams x 8 steps, honoring direction (uniform branch)
    float zst[4][8];
    {
      uint4 cur[4] = {zc0, zc1, zc2, zc3};
#pragma unroll
      for (int gg = 0; gg < 4; ++gg) {
        unsigned dw[4] = {cur[gg].x, cur[gg].y, cur[gg].z, cur[gg].w};
#pragma unroll
        for (int p = 0; p < 4; ++p) {
          float lo = __uint_as_float(dw[p] << 16);
          float hi = __uint_as_float(dw[p] & 0xFFFF0000u);
          if (dir) { zst[gg][7 - 2 * p] = lo; zst[gg][6 - 2 * p] = hi; }
          else     { zst[gg][2 * p] = lo;     zst[gg][2 * p + 1] = hi; }
        }
      }
    }
    // rotate prefetch
    uint4 zf0 = zn0, zf1 = zn1, zf2 = zn2, zf3 = zn3;
    {
      int gnext = (g8 + 2 < SQ / 8) ? (g8 + 2) : (SQ / 8 - 1);
      int rn = dir ? (SQ - 8 - 8 * gnext) : (8 * gnext);
      zn0 = *(const uint4*)(xi + rn);
      zn1 = *(const uint4*)(xf + rn);
      zn2 = *(const uint4*)(xg + rn);
      zn3 = *(const uint4*)(xo + rn);
    }
    float mva[8];
    if (hasMask) {
      float4 ma = mk4[2 * g8], mb = mk4[2 * g8 + 1];
      mva[0] = ma.x; mva[1] = ma.y; mva[2] = ma.z; mva[3] = ma.w;
      mva[4] = mb.x; mva[5] = mb.y; mva[6] = mb.z; mva[7] = mb.w;
    }
    bf16t hs8[8];
#pragma unroll
    for (int j = 0; j < 8; ++j) {
      const int par = j & 1;
      const uint4* hp = (const uint4*)&hbuf[par][0];
      uint4 q0 = hp[0], q1 = hp[1], q2 = hp[2], q3 = hp[3], q4 = hp[4], q5 = hp[5];
      unsigned qL = hbuf[par][24];
      unsigned hd[25] = {q0.x, q0.y, q0.z, q0.w, q1.x, q1.y, q1.z, q1.w,
                         q2.x, q2.y, q2.z, q2.w, q3.x, q3.y, q3.z, q3.w,
                         q4.x, q4.y, q4.z, q4.w, q5.x, q5.y, q5.z, q5.w, qL};
      float res[4];
#pragma unroll
      for (int gg = 0; gg < 4; ++gg) {
        float a0 = zst[gg][j], a1 = 0.f;
#pragma unroll
        for (int k2 = 0; k2 < 24; k2 += 2) {
          DOT2(hd[k2], wgt[gg][k2], a0)
          DOT2(hd[k2 + 1], wgt[gg][k2 + 1], a1)
        }
        DOT2(hd[24], wgt[gg][24], a0)
        res[gg] = a0 + a1;
      }
      float ai = sigm(res[0]);
      float af = sigm(res[1]);
      float ag = tanhx(res[2]);
      float ao = sigm(res[3]);
      c = af * c + ai * ag;
      float hn = ao * tanhx(c);
      if (act_l) {
        ((_Float16*)&hbuf[par ^ 1][0])[u] = (_Float16)hn;
        float mv = hasMask ? mva[j] : 1.f;
        hs8[j] = f2bf(hn * mv);
      }
    }
    if (act_l) {
      int t0 = 8 * g8;
#pragma unroll
      for (int j = 0; j < 8; ++j)
        outp[(size_t)(t0 + j) * 128 + u] = hs8[j];
    }
    zc0 = zf0; zc1 = zf1; zc2 = zf2; zc3 = zf3;
  }
}

// ---------------- attention (per timestep s) ----------------
// E1/E2 in LDS as packed f16 (E1 loaded per-half: 64 rows) -> 73 KB total LDS
// -> 2 blocks/CU (was 138 KB -> 1 block/CU).  GEMM1 via v_dot2_f32_f16; beta
// and GEMM2 accumulate in packed f16 (v_pk_fma_f16).  Ah stays f32.
__global__ __launch_bounds__(256) void attn_kernel(
    const bf16t* __restrict__ enc1, const bf16t* __restrict__ enc2,
    const float* __restrict__ m1, const float* __restrict__ m2,
    bf16t* __restrict__ d1b, bf16t* __restrict__ d2b) {
  const int s = blockIdx.x;
  const int tid = threadIdx.x;
  __shared__ __align__(16) _Float16 E1h[64][104];
  __shared__ __align__(16) _Float16 E2h[BB][104];
  __shared__ __align__(16) float Ah[64][APAD];
  __shared__ float mk1[BB], mk2[BB];
  __shared__ float rden[64];

  // load E2 (all 128 rows) as packed f16
  for (int idx = tid; idx < BB * 50; idx += 256) {
    int i = idx / 50, dp = idx - i * 50;
    unsigned uu = *(const unsigned*)&enc2[((size_t)i * SQ + s) * 128 + 2 * dp];
    half2t h;
    h[0] = (_Float16)__uint_as_float(uu << 16);
    h[1] = (_Float16)__uint_as_float(uu & 0xFFFF0000u);
    *(unsigned*)&E2h[i][2 * dp] = h2u(h);
  }
  {  // zero E2h pad cols 100..103 (2 dwords per row, 256 total)
    int i = tid >> 1, cpad = tid & 1;
    *(unsigned*)&E2h[i][100 + 2 * cpad] = 0u;
  }
  if (tid < BB) {
    mk1[tid] = m1[tid * SQ + s];
    mk2[tid] = m2[tid * SQ + s];
  }

  const int ti = tid >> 4, tjj = tid & 15;
  const int xj = tid & 127;
  const int xd0 = (tid >> 7) * 50;
  half2t N2[25];
#pragma unroll
  for (int q = 0; q < 25; ++q) N2[q] = (half2t){(_Float16)0.f, (_Float16)0.f};
  float Dacc = 0.f, M = -1e30f;

  for (int half = 0; half < 2; ++half) {
    const int r0 = half * 64;
    __syncthreads();  // protect E1h (prev beta) & Ah (prev GEMM2)
    // load E1 rows r0..r0+63 as packed f16
    for (int idx = tid; idx < 64 * 50; idx += 256) {
      int i = idx / 50, dp = idx - i * 50;
      unsigned uu = *(const unsigned*)&enc1[((size_t)(r0 + i) * SQ + s) * 128 + 2 * dp];
      half2t h;
      h[0] = (_Float16)__uint_as_float(uu << 16);
      h[1] = (_Float16)__uint_as_float(uu & 0xFFFF0000u);
      *(unsigned*)&E1h[i][2 * dp] = h2u(h);
    }
    if (tid < 128) {  // zero E1h pad cols 100..103
      int i = tid >> 1, cpad = tid & 1;
      *(unsigned*)&E1h[i][100 + 2 * cpad] = 0u;
    }
    __syncthreads();

    // --- GEMM1: Ah[i_local][j] = E1h[i_local] . E2h[j]  (f16 dot2, f32 acc)
    float acc[4][8];
#pragma unroll
    for (int ii = 0; ii < 4; ++ii)
#pragma unroll
      for (int jj = 0; jj < 8; ++jj) acc[ii][jj] = 0.f;
#pragma unroll
    for (int kc = 0; kc < 13; ++kc) {  // 8 f16 per chunk, cols 0..103 (pad=0)
      uint4 a4[4], b4[8];
#pragma unroll
      for (int ii = 0; ii < 4; ++ii)
        a4[ii] = *(const uint4*)&E1h[4 * ti + ii][8 * kc];
#pragma unroll
      for (int jj = 0; jj < 8; ++jj)
        b4[jj] = *(const uint4*)&E2h[tjj + 16 * jj][8 * kc];
#pragma unroll
      for (int ii = 0; ii < 4; ++ii)
#pragma unroll
        for (int jj = 0; jj < 8; ++jj) {
          DOT2(a4[ii].x, b4[jj].x, acc[ii][jj])
          DOT2(a4[ii].y, b4[jj].y, acc[ii][jj])
          DOT2(a4[ii].z, b4[jj].z, acc[ii][jj])
          DOT2(a4[ii].w, b4[jj].w, acc[ii][jj])
        }
    }
#pragma unroll
    for (int ii = 0; ii < 4; ++ii)
#pragma unroll
      for (int jj = 0; jj < 8; ++jj)
        Ah[4 * ti + ii][tjj + 16 * jj] = acc[ii][jj];
    __syncthreads();

    // --- beta: online accumulation over i (pk_fma in f16)
    {
      float lm = M;
      for (int i = 0; i < 64; ++i) lm = fmaxf(lm, Ah[i][xj]);
      float scale = __expf(M - lm);
      Dacc *= scale;
      half2t sc2 = f2h2(scale);
#pragma unroll
      for (int q = 0; q < 25; ++q) N2[q] *= sc2;
      for (int i = 0; i < 64; ++i) {
        float p = __expf(Ah[i][xj] - lm) * mk1[r0 + i];
        Dacc += p;
        half2t p2 = f2h2(p);
        const unsigned* e1p = (const unsigned*)&E1h[i][xd0];
#pragma unroll
        for (int q = 0; q < 25; ++q) N2[q] += u2h2(e1p[q]) * p2;
      }
      M = lm;
    }
    __syncthreads();

    // --- alpha row stats; overwrite Ah with p = exp(A - rowmax) * mk2[j]
    {
      int row = tid >> 2, seg = tid & 3;
      float mx = -1e30f;
      for (int q = 0; q < 32; ++q) mx = fmaxf(mx, Ah[row][seg + 4 * q]);
      mx = fmaxf(mx, __shfl_xor(mx, 1));
      mx = fmaxf(mx, __shfl_xor(mx, 2));
      float sm = 0.f;
      for (int q = 0; q < 32; ++q) {
        int jc = seg + 4 * q;
        float p = __expf(Ah[row][jc] - mx) * mk2[jc];
        Ah[row][jc] = p;
        sm += p;
      }
      sm += __shfl_xor(sm, 1);
      sm += __shfl_xor(sm, 2);
      if (seg == 0) rden[row] = sm + 1e-8f;
    }
    __syncthreads();

    // --- GEMM2: rows 4*ri.., col octets 8*cg (cg<13 active; f16 pk acc)
    {
      const int ri = tid >> 4, cg = tid & 15;
      half2t o2[4][4];
#pragma unroll
      for (int ii = 0; ii < 4; ++ii)
#pragma unroll
        for (int k = 0; k < 4; ++k) o2[ii][k] = (half2t){(_Float16)0.f, (_Float16)0.f};
      const int cgc = (cg < 13) ? cg : 0;
      for (int jb = 0; jb < BB; jb += 4) {
        float4 pv[4];
#pragma unroll
        for (int ii = 0; ii < 4; ++ii)
          pv[ii] = *(const float4*)&Ah[4 * ri + ii][jb];
        uint4 e4[4];
#pragma unroll
        for (int q = 0; q < 4; ++q)
          e4[q] = *(const uint4*)&E2h[jb + q][8 * cgc];
#pragma unroll
        for (int q = 0; q < 4; ++q) {
          unsigned ee[4] = {e4[q].x, e4[q].y, e4[q].z, e4[q].w};
#pragma unroll
          for (int ii = 0; ii < 4; ++ii) {
            float p = (q == 0) ? pv[ii].x : (q == 1) ? pv[ii].y
                     : (q == 2) ? pv[ii].z : pv[ii].w;
            half2t p2 = f2h2(p);
#pragma unroll
            for (int k = 0; k < 4; ++k) o2[ii][k] += u2h2(ee[k]) * p2;
          }
        }
      }
#pragma unroll
      for (int ii = 0; ii < 4; ++ii) {
        int i = r0 + 4 * ri + ii;
        float inv = 1.f / rden[4 * ri + ii];
        union { bf16t h[8]; uint4 u4; } pk;
        if (cg < 13) {
#pragma unroll
          for (int jj = 0; jj < 8; ++jj) {
            int d = 8 * cg + jj;
            float v = (float)o2[ii][jj >> 1][jj & 1] * inv;
            pk.h[jj] = (d < DD) ? f2bf(v) : (bf16t)0;
          }
        } else {
#pragma unroll
          for (int jj = 0; jj < 8; ++jj) pk.h[jj] = 0;
        }
        *(uint4*)&d1b[((size_t)i * SQ + s) * 128 + 8 * cg] = pk.u4;
      }
    }
  }
  float invD = 1.f / (Dacc + 1e-8f);
#pragma unroll
  for (int q = 0; q < 25; ++q) {
    float f0 = (float)N2[q][0] * invD;
    float f1 = (float)N2[q][1] * invD;
    union { bf16t h[2]; unsigned u; } pk;
    pk.h[0] = f2bf(f0);
    pk.h[1] = f2bf(f1);
    *(unsigned*)&d2b[((size_t)xj * SQ + s) * 128 + xd0 + 2 * q] = pk.u;
  }
  if (xd0 == 50) {
#pragma unroll
    for (int q = 0; q < 14; ++q)
      *(unsigned*)&d2b[((size_t)xj * SQ + s) * 128 + 100 + 2 * q] = 0u;
  }
}

// ---------------- masked pooling (cmp stride 128) ----------------
__global__ __launch_bounds__(128) void pool_kernel(
    const bf16t* __restrict__ cmp1, const bf16t* __restrict__ cmp2,
    const float* __restrict__ m1, const float* __restrict__ m2,
    float* __restrict__ pooled) {
  int b = blockIdx.x & 127, inp = blockIdx.x >> 7;
  const bf16t* C = (inp ? cmp2 : cmp1) + (size_t)b * SQ * 128;
  const float* M = (inp ? m2 : m1) + b * SQ;
  int f = threadIdx.x;
  float ms = 0.f;
  for (int s = f; s < SQ; s += 128) ms += M[s];
  __shared__ float red[128];
  red[f] = ms;
  __syncthreads();
  for (int o = 64; o > 0; o >>= 1) {
    if (f < o) red[f] += red[f + o];
    __syncthreads();
  }
  float msum = red[0];
  if (f < 100) {
    float sm = 0.f, mx = -1e30f;
    for (int s = 0; s < SQ; ++s) {
      float v = bf2f(C[(size_t)s * 128 + f]) * M[s];
      sm += v;
      mx = fmaxf(mx, v);
    }
    pooled[b * 400 + inp * 200 + f] = sm / msum;
    pooled[b * 400 + inp * 200 + 100 + f] = mx;
  }
}

// ---------------- final MLP + softmax ----------------
__global__ __launch_bounds__(128) void final_kernel(
    const float* __restrict__ pooled, const float* __restrict__ W1,
    const float* __restrict__ b1, const float* __restrict__ W2,
    const float* __restrict__ b2, float* __restrict__ out) {
  int b = blockIdx.x;
  int j = threadIdx.x;
  __shared__ float pr[400];
  __shared__ float h[100];
  for (int idx = j; idx < 400; idx += 128) pr[idx] = pooled[b * 400 + idx];
  __syncthreads();
  if (j < 100) {
    float a = b1[j];
    for (int k = 0; k < 400; ++k) a += pr[k] * W1[k * 100 + j];
    h[j] = tanhx(a);
  }
  __syncthreads();
  if (j == 0) {
    float l0 = b2[0], l1 = b2[1];
    for (int k = 0; k < 100; ++k) {
      l0 += h[k] * W2[k * 2];
      l1 += h[k] * W2[k * 2 + 1];
    }
    float mx = fmaxf(l0, l1);
    float e0 = __expf(l0 - mx), e1 = __expf(l1 - mx);
    float inv = 1.f / (e0 + e1);
    out[b * 2] = e0 * inv;
    out[b * 2 + 1] = e1 * inv;
  }
}

extern "C" void kernel_launch(void* const* d_in, const int* in_sizes, int n_in,
                              void* d_out, int out_size, void* d_ws, size_t ws_size,
                              hipStream_t stream) {
  const int* x1 = (const int*)d_in[0];
  const int* x2 = (const int*)d_in[1];
  const float* emb = (const float*)d_in[2];
  const float* b1f_Wx = (const float*)d_in[3];
  const float* b1f_Wh = (const float*)d_in[4];
  const float* b1f_b = (const float*)d_in[5];
  const float* b1b_Wx = (const float*)d_in[6];
  const float* b1b_Wh = (const float*)d_in[7];
  const float* b1b_b = (const float*)d_in[8];
  const float* dense_W = (const float*)d_in[9];
  const float* dense_b = (const float*)d_in[10];
  const float* b2f_Wx = (const float*)d_in[11];
  const float* b2f_Wh = (const float*)d_in[12];
  const float* b2f_b = (const float*)d_in[13];
  const float* b2b_Wx = (const float*)d_in[14];
  const float* b2b_Wh = (const float*)d_in[15];
  const float* b2b_b = (const float*)d_in[16];
  const float* dense1_W = (const float*)d_in[17];
  const float* dense1_b = (const float*)d_in[18];
  const float* out_W = (const float*)d_in[19];
  const float* out_b = (const float*)d_in[20];
  float* out = (float*)d_out;

  // ---- workspace layout (~173 MB) ----
  char* base = (char*)d_ws;
  bf16t* xz = (bf16t*)base;               // xzT [4][128][200][512]
  bf16t* d1b = (bf16t*)base;
  bf16t* d2b = d1b + (size_t)TOKN * 128;
  char* r1 = base + (size_t)4 * TOKN * 200 * 2;
  bf16t* enc1 = (bf16t*)r1;
  bf16t* enc2 = enc1 + (size_t)TOKN * 128;
  bf16t* e1b = (bf16t*)r1;
  bf16t* e2b = e1b + (size_t)TOKN * 64;
  char* r2 = r1 + (size_t)2 * TOKN * 128 * 2;
  bf16t* map1 = (bf16t*)r2;
  bf16t* map2 = map1 + (size_t)TOKN * 128;
  char* r3 = r2 + (size_t)2 * TOKN * 128 * 2;
  float* m1 = (float*)r3;
  float* m2 = m1 + TOKN;
  float* pooled = m2 + TOKN;
  bf16t* w1T = (bf16t*)(r3 + ((size_t)2 * TOKN + 128 * 400) * 4);
  bf16t* w2T = w1T + 2 * 208 * 64;
  bf16t* wdT = w2T + 2 * 208 * 128;
  unsigned* whP = (unsigned*)(wdT + 128 * 384);  // [4][25][200] packed half2
  bf16t* cmp1 = enc1;
  bf16t* cmp2 = enc2;
  (void)in_sizes; (void)n_in; (void)out_size; (void)ws_size;

  embed_kernel<<<dim3(TOKN * 64 / 256, 2), 256, 0, stream>>>(
      x1, x2, emb, e1b, e2b, m1, m2);
  wprep_kernel<<<dim3(208, 4), 256, 0, stream>>>(
      b1f_Wx, b1b_Wx, b2f_Wx, b2b_Wx, dense_W,
      b1f_Wh, b1b_Wh, b2f_Wh, b2b_Wh, w1T, w2T, wdT, whP);
  xz_mfma<64><<<dim3(TOKN / 64, 4), 256, 0, stream>>>(
      e1b, e2b, w1T, b1f_b, b1b_b, xz);
  padzero_kernel<<<(TOKN * 14 + 255) / 256, 256, 0, stream>>>(
      (unsigned*)enc1, (unsigned*)enc2);
  lstm_scan<<<512, 64, 0, stream>>>(xz, whP, enc1, enc2, m1, m2, 1);
  attn_kernel<<<SQ, 256, 0, stream>>>(enc1, enc2, m1, m2, d1b, d2b);
  dense_mfma<<<dim3(TOKN / 64, 2), 256, 0, stream>>>(
      enc1, enc2, d1b, d2b, wdT, dense_b, map1, map2);
  xz_mfma<128><<<dim3(TOKN / 64, 4), 256, 0, stream>>>(
      map1, map2, w2T, b2f_b, b2b_b, xz);
  lstm_scan<<<512, 64, 0, stream>>>(xz, whP + 2 * 5000, cmp1, cmp2, m1, m2, 0);
  pool_kernel<<<256, 128, 0, stream>>>(cmp1, cmp2, m1, m2, pooled);
  final_kernel<<<128, 128, 0, stream>>>(pooled, dense1_W, dense1_b, out_W, out_b, out);
}